// Round 12
// baseline (284.407 us; speedup 1.0000x reference)
//
#include <hip/hip_runtime.h>
#include <stdint.h>

#define M_DIM 8192
#define N_DIM 4096
#define K_DIM 4096
#define CBN   (K_DIM/8)   // 512 column groups per row

typedef __attribute__((ext_vector_type(8))) short bf16x8;
typedef __attribute__((ext_vector_type(8))) unsigned short u16x8;
typedef __attribute__((ext_vector_type(4))) float f32x4;

#define AS_GLOBAL(p) (const __attribute__((address_space(1))) void*)(p)
#define AS_LDS(p)    (__attribute__((address_space(3))) void*)(p)

static __device__ __forceinline__ unsigned short f2bf(float f) {
    union { float f; uint32_t u; } c; c.f = f;
    uint32_t u = c.u;
    return (unsigned short)((u + 0x7fffu + ((u >> 16) & 1u)) >> 16);
}

// ---------------------------------------------------------------------------
// Kernel 1: per (ob, cb) pick top-4 columns (of 8) by L1 mass over 64 rows.
// ---------------------------------------------------------------------------
__global__ __launch_bounds__(256) void venom_sel(const float* __restrict__ W,
                                                 uint16_t* __restrict__ sel) {
    int t   = threadIdx.x;
    int ob  = blockIdx.x;
    int col = blockIdx.y * 256 + t;
    const float* p = W + (size_t)(ob * 64) * K_DIM + col;
    double s = 0.0;
    #pragma unroll 16
    for (int r = 0; r < 64; ++r) s += fabsf(p[(size_t)r * K_DIM]);

    int lane = t & 63;
    int base = lane & ~7;
    double sc[8];
    #pragma unroll
    for (int j = 0; j < 8; ++j) sc[j] = __shfl(s, base + j, 64);

    uint32_t packed = 0;
    #pragma unroll
    for (int c = 0; c < 8; ++c) {
        int rank = 0;
        #pragma unroll
        for (int j = 0; j < 8; ++j)
            rank += (sc[j] > sc[c]) || (sc[j] == sc[c] && j < c);
        if (rank < 4) packed |= (uint32_t)c << (4 * rank);
    }
    if ((lane & 7) == 0) {
        int cb = col >> 3;
        sel[ob * CBN + cb] = (uint16_t)packed;
    }
}

// ---------------------------------------------------------------------------
// Kernel 2: masked bf16 weight pack (top-2 of selected 4 by |w|).
// ---------------------------------------------------------------------------
__global__ __launch_bounds__(256) void venom_pack(const float* __restrict__ W,
                                                  const uint16_t* __restrict__ sel,
                                                  unsigned short* __restrict__ Wb) {
    int gid = blockIdx.x * 256 + threadIdx.x;
    int o  = gid >> 9;
    int cb = gid & (CBN - 1);
    uint32_t pk = sel[(o >> 6) * CBN + cb];
    const float* p = W + (size_t)o * K_DIM + cb * 8;
    float4 a = *(const float4*)p;
    float4 b = *(const float4*)(p + 4);
    float w[8] = {a.x, a.y, a.z, a.w, b.x, b.y, b.z, b.w};

    int   c[4]; float v[4];
    #pragma unroll
    for (int pz = 0; pz < 4; ++pz) {
        c[pz] = (pk >> (4 * pz)) & 7;
        v[pz] = fabsf(w[c[pz]]);
    }
    uint32_t keep = 0;
    #pragma unroll
    for (int pz = 0; pz < 4; ++pz) {
        int cnt = 0;
        #pragma unroll
        for (int q = 0; q < 4; ++q)
            cnt += (v[q] > v[pz]) || (v[q] == v[pz] && q < pz);
        if (cnt < 2) keep |= 1u << c[pz];
    }
    u16x8 out;
    #pragma unroll
    for (int j = 0; j < 8; ++j)
        out[j] = f2bf(((keep >> j) & 1) ? w[j] : 0.0f);
    *(u16x8*)(Wb + (size_t)gid * 8) = out;
}

// ---------------------------------------------------------------------------
// Kernel 3: x f32 -> bf16 (RNE).
// ---------------------------------------------------------------------------
__global__ __launch_bounds__(256) void xcvt(const float* __restrict__ X,
                                            unsigned short* __restrict__ Xb) {
    size_t gid = (size_t)blockIdx.x * 256 + threadIdx.x;
    const float4* p = (const float4*)X + gid * 2;
    float4 a = p[0], b = p[1];
    float w[8] = {a.x, a.y, a.z, a.w, b.x, b.y, b.z, b.w};
    u16x8 out;
    #pragma unroll
    for (int j = 0; j < 8; ++j) out[j] = f2bf(w[j]);
    *(u16x8*)(Xb + gid * 8) = out;
}

// ---------------------------------------------------------------------------
// Kernel 4: 256x256 bf16 GEMM, PARITY-SPLIT separated loops (round-11
// structure) with a MAPPING-ROBUST parity:
//   wm = (wid ^ (wid>>2)) & 1, wn = wid >> 1   (bijective remap)
// Under SIMD mapping wid%4 (SIMD k = {k,k+4}): parities differ in bit2 ->
// one read-phase + one MFMA-phase wave per SIMD. Under mapping wid>>1
// (SIMD k = {2k,2k+1}): parities differ in bit0 -> same property. Round 9/11
// used wm=wid>>2, which fails under the wid>>1 mapping (both parities equal
// per SIMD -> no overlap -> the measured ~50% MfmaUtil plateau).
//   wm==0 loop: SP s = { read s | stage s+3 | lgkm(0) | 32 MFMA | vmcnt | BAR }
//   wm==1 loop: SP s = { lgkm(0) | 32 MFMA (frags from tail of s-1)
//                        | read s+1 | stage s+3 | vmcnt | BAR }
// Ledger (identical to rounds 10/11, both PASSED):
//   R-after-W: wm0 reads s @SP s: staged @s-3, drained CKPT4@s-2 + BAR.
//     wm1 reads s+1 @tail of SP s: staged @s-2, drained CKPT4@s-1 + BAR@s-1.
//   W-after-R: stage@s overwrites region of s-1; wm0 read it @top s-1,
//     wm1 @tail s-2 (drained by their lgkm0 @top s-1) -> both < BAR@s-1.
//   Tail: CKPT4@124 (drains stage@123=slice126), CKPT0@125 (drains
//     stage@124=slice127), none @126/127. Barrier counts equal in both loops.
// Frags 16x16x32 (0 conflicts); XOR chunk swizzle; XCD block swizzle.
// ---------------------------------------------------------------------------
__global__ __launch_bounds__(512, 2) void gemm256(const unsigned short* __restrict__ A,
                                                  const unsigned short* __restrict__ B,
                                                  const float* __restrict__ bias,
                                                  float* __restrict__ C) {
    __shared__ __align__(16) unsigned char smem[131072]; // A:[0,64K) B:[64K,128K)

    int t    = threadIdx.x;
    int wid  = t >> 6;
    int lane = t & 63;
    int l16  = lane & 15;
    int lk   = lane >> 4;
    int wm   = (wid ^ (wid >> 2)) & 1;  // schedule parity == output row-half
    int wn   = wid >> 1;                // wave col-quarter (64 cols)

    // XCD-aware bijective swizzle (512 blocks % 8 == 0)
    int bid = blockIdx.x;
    int swz = (bid & 7) * ((int)gridDim.x >> 3) + (bid >> 3);
    int bm  = swz >> 4;
    int bn  = swz & 15;

    // staging: thread t covers row r=t>>2 (and r+128), phys chunk t&3 holds
    // logical chunk (t&3)^((r>>1)&3) = (t&3)^((t>>3)&3)
    int gch = ((t & 3) ^ ((t >> 3) & 3)) * 8;
    const unsigned short* agbase = A + (size_t)(bm * 256 + (t >> 2)) * K_DIM + gch;
    const unsigned short* bgbase = B + (size_t)(bn * 256 + (t >> 2)) * K_DIM + gch;

    auto stageA2 = [&](int slice) {
        const unsigned short* ga = agbase + slice * 32;
        char* la = (char*)smem + (slice & 3) * 16384 + wid * 1024;
        __builtin_amdgcn_global_load_lds(AS_GLOBAL(ga), AS_LDS(la), 16, 0, 0);
        __builtin_amdgcn_global_load_lds(AS_GLOBAL(ga + (size_t)128 * K_DIM), AS_LDS(la + 8192), 16, 0, 0);
    };
    auto stageB2 = [&](int slice) {
        const unsigned short* gb = bgbase + slice * 32;
        char* lb = (char*)smem + 65536 + (slice & 3) * 16384 + wid * 1024;
        __builtin_amdgcn_global_load_lds(AS_GLOBAL(gb), AS_LDS(lb), 16, 0, 0);
        __builtin_amdgcn_global_load_lds(AS_GLOBAL(gb + (size_t)128 * K_DIM), AS_LDS(lb + 8192), 16, 0, 0);
    };

    // read-side: row R = base+l16, k-chunk lk -> phys chunk lk^((l16>>1)&3)
    int koff = ((lk ^ ((l16 >> 1) & 3)) << 4);
    const char* ardb = (const char*)smem + (wm * 128 + l16) * 64 + koff;
    const char* brdb = (const char*)smem + 65536 + (wn * 64 + l16) * 64 + koff;

    f32x4 acc[8][4] = {};
    bf16x8 af0[4], af1[4], bfr[4];

#define LGKM0() { asm volatile("s_waitcnt lgkmcnt(0)" ::: "memory");                 \
                  __builtin_amdgcn_sched_barrier(0); }
#define CKPT4() { asm volatile("s_waitcnt vmcnt(4)" ::: "memory");                   \
                  __builtin_amdgcn_sched_barrier(0); }
#define CKPT0() { asm volatile("s_waitcnt vmcnt(0)" ::: "memory");                   \
                  __builtin_amdgcn_sched_barrier(0); }
#define BAR()   { __builtin_amdgcn_s_barrier(); __builtin_amdgcn_sched_barrier(0); }

#define RDNXT(RN)                                                                    \
    {                                                                                \
        _Pragma("unroll")                                                            \
        for (int g = 0; g < 4; ++g)                                                  \
            bfr[g] = *(const bf16x8*)(brdb + (RN) * 16384 + g * 1024);               \
        _Pragma("unroll")                                                            \
        for (int i = 0; i < 4; ++i)                                                  \
            af0[i] = *(const bf16x8*)(ardb + (RN) * 16384 + i * 1024);               \
        _Pragma("unroll")                                                            \
        for (int i = 0; i < 4; ++i)                                                  \
            af1[i] = *(const bf16x8*)(ardb + (RN) * 16384 + 4096 + i * 1024);        \
        __builtin_amdgcn_sched_barrier(0);                                           \
    }

#define MFMA32()                                                                     \
    {                                                                                \
        __builtin_amdgcn_s_setprio(1);                                               \
        _Pragma("unroll")                                                            \
        for (int i = 0; i < 4; ++i)                                                  \
            _Pragma("unroll")                                                        \
            for (int g = 0; g < 4; ++g)                                              \
                acc[i][g] = __builtin_amdgcn_mfma_f32_16x16x32_bf16(af0[i], bfr[g], acc[i][g], 0, 0, 0); \
        _Pragma("unroll")                                                            \
        for (int i = 0; i < 4; ++i)                                                  \
            _Pragma("unroll")                                                        \
            for (int g = 0; g < 4; ++g)                                              \
                acc[4+i][g] = __builtin_amdgcn_mfma_f32_16x16x32_bf16(af1[i], bfr[g], acc[4+i][g], 0, 0, 0); \
        __builtin_amdgcn_s_setprio(0);                                               \
        __builtin_amdgcn_sched_barrier(0);                                           \
    }

    // wm==0: reads at top.  RC = region of slice s.
#define SP0(RC, DOSTAGE, SS, CK)                                                     \
    {                                                                                \
        RDNXT(RC)                                                                    \
        if (DOSTAGE) { stageA2(SS); stageB2(SS); }                                   \
        LGKM0()                                                                      \
        MFMA32()                                                                     \
        if ((CK) == 4) { CKPT4() } else if ((CK) == 1) { CKPT0() }                   \
        BAR()                                                                        \
    }
    // wm==1: reads at tail (slice s+1, region RNX), MFMA on prev-tail frags.
#define SP1(RNX, DORD, DOSTAGE, SS, CK)                                              \
    {                                                                                \
        LGKM0()                                                                      \
        MFMA32()                                                                     \
        if (DORD) RDNXT(RNX)                                                         \
        if (DOSTAGE) { stageA2(SS); stageB2(SS); }                                   \
        if ((CK) == 4) { CKPT4() } else if ((CK) == 1) { CKPT0() }                   \
        BAR()                                                                        \
    }

    // prologue (all waves): stage slices 0,1,2; drain 0,1; barrier.
    stageA2(0); stageB2(0);
    stageA2(1); stageB2(1);
    stageA2(2); stageB2(2);
    CKPT4()
    BAR()

    if (wm == 0) {
        // reads-at-top loop
        for (int s4 = 0; s4 < 31; ++s4) {
            int s = s4 * 4;
            SP0(0, 1, s + 3, 4)
            SP0(1, 1, s + 4, 4)
            SP0(2, 1, s + 5, 4)
            SP0(3, 1, s + 6, 4)
        }
        SP0(0, 1, 127, 4)    // s=124: stage 127; drain stage@123 (slice 126)
        SP0(1, 0, 0,   1)    // s=125: CKPT0 drains stage@124 (slice 127)
        SP0(2, 0, 0,   0)    // s=126
        SP0(3, 0, 0,   0)    // s=127
    } else {
        // reads-at-tail loop (pre-read slice 0 after prologue barrier)
        RDNXT(0)
        for (int s4 = 0; s4 < 31; ++s4) {
            int s = s4 * 4;
            SP1(1, 1, 1, s + 3, 4)
            SP1(2, 1, 1, s + 4, 4)
            SP1(3, 1, 1, s + 5, 4)
            SP1(0, 1, 1, s + 6, 4)
        }
        SP1(1, 1, 1, 127, 4)  // s=124
        SP1(2, 1, 0, 0,   1)  // s=125
        SP1(3, 1, 0, 0,   0)  // s=126: tail-reads slice 127
        SP1(0, 0, 0, 0,   0)  // s=127: no reads after
    }

    // epilogue: C/D layout col = lane&15, row = (lane>>4)*4 + reg
    int    colb = bn * 256 + wn * 64;
    size_t rowb = (size_t)bm * 256 + wm * 128 + (lk << 2);
    #pragma unroll
    for (int g = 0; g < 4; ++g) {
        int col = colb + g * 16 + l16;
        float bv = bias[col];
        #pragma unroll
        for (int f = 0; f < 8; ++f) {
            size_t r0 = rowb + f * 16;
            #pragma unroll
            for (int rg = 0; rg < 4; ++rg)
                C[(r0 + rg) * N_DIM + col] = acc[f][g][rg] + bv;
        }
    }
}

extern "C" void kernel_launch(void* const* d_in, const int* in_sizes, int n_in,
                              void* d_out, int out_size, void* d_ws, size_t ws_size,
                              hipStream_t stream) {
    const float* x    = (const float*)d_in[0];
    const float* W    = (const float*)d_in[1];
    const float* bias = (const float*)d_in[2];
    float* out = (float*)d_out;

    char* ws = (char*)d_ws;
    unsigned short* xb  = (unsigned short*)ws;                                   // 64 MB
    unsigned short* wb  = (unsigned short*)(ws + (size_t)M_DIM * K_DIM * 2);     // 32 MB
    uint16_t*       sel = (uint16_t*)(ws + (size_t)M_DIM * K_DIM * 2
                                         + (size_t)N_DIM * K_DIM * 2);           // 64 KB

    venom_sel <<<dim3(64, 16), 256, 0, stream>>>(W, sel);
    venom_pack<<<dim3((N_DIM * CBN) / 256), 256, 0, stream>>>(W, sel, wb);
    xcvt      <<<dim3((M_DIM * K_DIM / 8) / 256), 256, 0, stream>>>(x, xb);
    gemm256   <<<dim3((M_DIM / 256) * (N_DIM / 256)), 512, 0, stream>>>(xb, wb, bias, out);
}

// Round 13
// 196.813 us; speedup vs baseline: 1.4451x; 1.4451x over previous
//
#include <hip/hip_runtime.h>
#include <stdint.h>

#define M_DIM 8192
#define N_DIM 4096
#define K_DIM 4096
#define CBN   (K_DIM/8)   // 512 column groups per row

typedef __attribute__((ext_vector_type(4)))  int   i32x4;
typedef __attribute__((ext_vector_type(16))) char  i8x16;

#define AS_GLOBAL(p) (const __attribute__((address_space(1))) void*)(p)
#define AS_LDS(p)    (__attribute__((address_space(3))) void*)(p)

// ---------------------------------------------------------------------------
// Kernel 1: per (ob, cb) pick top-4 columns (of 8) by L1 mass over 64 rows.
// (unchanged — mask decided on exact f32 weights)
// ---------------------------------------------------------------------------
__global__ __launch_bounds__(256) void venom_sel(const float* __restrict__ W,
                                                 uint16_t* __restrict__ sel) {
    int t   = threadIdx.x;
    int ob  = blockIdx.x;
    int col = blockIdx.y * 256 + t;
    const float* p = W + (size_t)(ob * 64) * K_DIM + col;
    double s = 0.0;
    #pragma unroll 16
    for (int r = 0; r < 64; ++r) s += fabsf(p[(size_t)r * K_DIM]);

    int lane = t & 63;
    int base = lane & ~7;
    double sc[8];
    #pragma unroll
    for (int j = 0; j < 8; ++j) sc[j] = __shfl(s, base + j, 64);

    uint32_t packed = 0;
    #pragma unroll
    for (int c = 0; c < 8; ++c) {
        int rank = 0;
        #pragma unroll
        for (int j = 0; j < 8; ++j)
            rank += (sc[j] > sc[c]) || (sc[j] == sc[c] && j < c);
        if (rank < 4) packed |= (uint32_t)c << (4 * rank);
    }
    if ((lane & 7) == 0) {
        int cb = col >> 3;
        sel[ob * CBN + cb] = (uint16_t)packed;
    }
}

// ---------------------------------------------------------------------------
// Kernel 2: masked weight -> int8 with per-output-row symmetric scale.
// One block per output row o; thread handles 2 column-groups (16 values).
// Same top-2-of-selected-4 keep logic as the verified bf16 version.
// ---------------------------------------------------------------------------
__global__ __launch_bounds__(256) void venom_packq(const float* __restrict__ W,
                                                   const uint16_t* __restrict__ sel,
                                                   int8_t* __restrict__ Wq,
                                                   float* __restrict__ sw) {
    __shared__ float red[4];
    int o = blockIdx.x;
    const float* rowp = W + (size_t)o * K_DIM;
    float mv[16];
    float m = 0.0f;
    #pragma unroll
    for (int h = 0; h < 2; ++h) {
        int cb = threadIdx.x * 2 + h;
        uint32_t pk = sel[(o >> 6) * CBN + cb];
        const float* p = rowp + cb * 8;
        float4 a = *(const float4*)p;
        float4 b = *(const float4*)(p + 4);
        float w[8] = {a.x, a.y, a.z, a.w, b.x, b.y, b.z, b.w};
        int   c[4]; float v[4];
        #pragma unroll
        for (int pz = 0; pz < 4; ++pz) {
            c[pz] = (pk >> (4 * pz)) & 7;
            v[pz] = fabsf(w[c[pz]]);
        }
        uint32_t keep = 0;
        #pragma unroll
        for (int pz = 0; pz < 4; ++pz) {
            int cnt = 0;
            #pragma unroll
            for (int q = 0; q < 4; ++q)
                cnt += (v[q] > v[pz]) || (v[q] == v[pz] && q < pz);
            if (cnt < 2) keep |= 1u << c[pz];
        }
        #pragma unroll
        for (int j = 0; j < 8; ++j) {
            float x = ((keep >> j) & 1) ? w[j] : 0.0f;
            mv[h * 8 + j] = x;
            m = fmaxf(m, fabsf(x));
        }
    }
    // block max-reduce
    #pragma unroll
    for (int off = 32; off >= 1; off >>= 1) m = fmaxf(m, __shfl_xor(m, off, 64));
    int lane = threadIdx.x & 63, wid = threadIdx.x >> 6;
    if (lane == 0) red[wid] = m;
    __syncthreads();
    m = fmaxf(fmaxf(red[0], red[1]), fmaxf(red[2], red[3]));
    float inv = m > 0.0f ? 127.0f / m : 0.0f;

    i8x16 q;
    #pragma unroll
    for (int j = 0; j < 16; ++j) {
        float qq = rintf(mv[j] * inv);
        qq = fminf(127.0f, fmaxf(-127.0f, qq));
        q[j] = (char)(int)qq;
    }
    *(i8x16*)(Wq + (size_t)o * K_DIM + threadIdx.x * 16) = q;
    if (threadIdx.x == 0) sw[o] = m > 0.0f ? m / 127.0f : 1.0f;
}

// ---------------------------------------------------------------------------
// Kernel 3: x f32 -> int8 with per-row symmetric scale. One block per row.
// ---------------------------------------------------------------------------
__global__ __launch_bounds__(256) void xq_kernel(const float* __restrict__ X,
                                                 int8_t* __restrict__ Xq,
                                                 float* __restrict__ sx) {
    __shared__ float red[4];
    int row = blockIdx.x;
    const float4* p = (const float4*)(X + (size_t)row * K_DIM) + threadIdx.x * 4;
    float4 v0 = p[0], v1 = p[1], v2 = p[2], v3 = p[3];
    float vv[16] = {v0.x, v0.y, v0.z, v0.w, v1.x, v1.y, v1.z, v1.w,
                    v2.x, v2.y, v2.z, v2.w, v3.x, v3.y, v3.z, v3.w};
    float m = 0.0f;
    #pragma unroll
    for (int j = 0; j < 16; ++j) m = fmaxf(m, fabsf(vv[j]));
    #pragma unroll
    for (int off = 32; off >= 1; off >>= 1) m = fmaxf(m, __shfl_xor(m, off, 64));
    int lane = threadIdx.x & 63, wid = threadIdx.x >> 6;
    if (lane == 0) red[wid] = m;
    __syncthreads();
    m = fmaxf(fmaxf(red[0], red[1]), fmaxf(red[2], red[3]));
    float inv = m > 0.0f ? 127.0f / m : 0.0f;

    i8x16 q;
    #pragma unroll
    for (int j = 0; j < 16; ++j) {
        float qq = rintf(vv[j] * inv);
        qq = fminf(127.0f, fmaxf(-127.0f, qq));
        q[j] = (char)(int)qq;
    }
    *(i8x16*)(Xq + (size_t)row * K_DIM + threadIdx.x * 16) = q;
    if (threadIdx.x == 0) sx[row] = m > 0.0f ? m / 127.0f : 1.0f;
}

// ---------------------------------------------------------------------------
// Kernel 4: 256x256 int8 GEMM (mfma_i32_16x16x64_i8, 2x bf16 rate, half the
// LDS bytes/FLOP). Round-7 super-phase structure (best bf16 schedule) with
// BK=64-byte slices, regions mod 4 (4 x 16KB A + 4 x 16KB B = 128KB):
//   SP s: { 12 ds_read (bfr, af0, af1) from region s&3 | stageA(s+2) |
//           lgkm(4) | 16 MFMA Mh0 | stageB(s+2) | lgkm(0) | 16 MFMA Mh1 |
//           vmcnt(4) | s_barrier }
// LDS byte-geometry identical to the bf16 kernel (64B rows, 4x16B chunks) ->
// same XOR chunk swizzle (0 conflicts), same staging pattern, same ledger:
//   R@SP s (region s&3): staged @s-2, drained by CKPT4 @s-1 (outstanding 8
//   -> oldest 4 = slice s) + BAR. W-after-R: stage s+2 overwrites region of
//   slice s-2, read @SP s-2, lgkm(0)-drained 2 barriers earlier.
//   Tail: SP62 CKPT0 (drains stage@61 = slice 63), SP63 no stage/no CKPT.
// Any internal k-permutation of the i8 fragment is harmless: A and B use the
// same lane->k map, so the dot product is invariant.
// Epilogue: C = sx[row]*sw[col]*acc + bias (f32).
// ---------------------------------------------------------------------------
__global__ __launch_bounds__(512, 2) void gemm256_i8(const int8_t* __restrict__ A,
                                                     const int8_t* __restrict__ B,
                                                     const float* __restrict__ sx,
                                                     const float* __restrict__ sw,
                                                     const float* __restrict__ bias,
                                                     float* __restrict__ C) {
    __shared__ __align__(16) unsigned char smem[131072]; // A:[0,64K) B:[64K,128K)

    int t    = threadIdx.x;
    int wid  = t >> 6;
    int lane = t & 63;
    int l16  = lane & 15;
    int lk   = lane >> 4;
    int wm   = wid >> 2;     // wave row-half (128 rows)
    int wn   = wid & 3;      // wave col-quarter (64 cols)

    // XCD-aware bijective swizzle (512 blocks % 8 == 0)
    int bid = blockIdx.x;
    int swz = (bid & 7) * ((int)gridDim.x >> 3) + (bid >> 3);
    int bm  = swz >> 4;
    int bn  = swz & 15;

    // staging: thread t covers row r=t>>2 (and r+128); stored 16B chunk t&3
    // holds logical chunk (t&3)^((r>>1)&3) = (t&3)^((t>>3)&3)   (bytes now)
    int gch = ((t & 3) ^ ((t >> 3) & 3)) * 16;
    const int8_t* agbase = A + (size_t)(bm * 256 + (t >> 2)) * K_DIM + gch;
    const int8_t* bgbase = B + (size_t)(bn * 256 + (t >> 2)) * K_DIM + gch;

    auto stageA2 = [&](int slice) {
        const int8_t* ga = agbase + slice * 64;
        char* la = (char*)smem + (slice & 3) * 16384 + wid * 1024;
        __builtin_amdgcn_global_load_lds(AS_GLOBAL(ga), AS_LDS(la), 16, 0, 0);
        __builtin_amdgcn_global_load_lds(AS_GLOBAL(ga + (size_t)128 * K_DIM), AS_LDS(la + 8192), 16, 0, 0);
    };
    auto stageB2 = [&](int slice) {
        const int8_t* gb = bgbase + slice * 64;
        char* lb = (char*)smem + 65536 + (slice & 3) * 16384 + wid * 1024;
        __builtin_amdgcn_global_load_lds(AS_GLOBAL(gb), AS_LDS(lb), 16, 0, 0);
        __builtin_amdgcn_global_load_lds(AS_GLOBAL(gb + (size_t)128 * K_DIM), AS_LDS(lb + 8192), 16, 0, 0);
    };

    // read-side: row R = base+l16, 16B chunk lk -> phys chunk lk^((l16>>1)&3)
    int koff = ((lk ^ ((l16 >> 1) & 3)) << 4);
    const char* ardb = (const char*)smem + (wm * 128 + l16) * 64 + koff;
    const char* brdb = (const char*)smem + 65536 + (wn * 64 + l16) * 64 + koff;

    i32x4 acc[8][4] = {};
    i32x4 af0[4], af1[4], bfr[4];

#define LGKM(N) { asm volatile("s_waitcnt lgkmcnt(" #N ")" ::: "memory");            \
                  __builtin_amdgcn_sched_barrier(0); }
#define CKPT4() { asm volatile("s_waitcnt vmcnt(4)" ::: "memory");                   \
                  __builtin_amdgcn_sched_barrier(0); }
#define CKPT0() { asm volatile("s_waitcnt vmcnt(0)" ::: "memory");                   \
                  __builtin_amdgcn_sched_barrier(0); }
#define BAR()   { __builtin_amdgcn_s_barrier(); __builtin_amdgcn_sched_barrier(0); }

    // SP body. RN: region (s&3). SS: slice staged (s+2). DOSTAGE. CK: 4/1/0.
#define SP(RN, SS, DOSTAGE, CK)                                                      \
    {                                                                                \
        const char* abase = ardb + (RN) * 16384;                                     \
        const char* bbase = brdb + (RN) * 16384;                                     \
        _Pragma("unroll")                                                            \
        for (int g = 0; g < 4; ++g) bfr[g] = *(const i32x4*)(bbase + g * 1024);      \
        _Pragma("unroll")                                                            \
        for (int i = 0; i < 4; ++i) af0[i] = *(const i32x4*)(abase + i * 1024);      \
        _Pragma("unroll")                                                            \
        for (int i = 0; i < 4; ++i) af1[i] = *(const i32x4*)(abase + 4096 + i * 1024); \
        if (DOSTAGE) stageA2(SS);                                                    \
        LGKM(4)                                                                      \
        __builtin_amdgcn_s_setprio(1);                                               \
        _Pragma("unroll")                                                            \
        for (int i = 0; i < 4; ++i)                                                  \
            _Pragma("unroll")                                                        \
            for (int g = 0; g < 4; ++g)                                              \
                acc[i][g] = __builtin_amdgcn_mfma_i32_16x16x64_i8(af0[i], bfr[g], acc[i][g], 0, 0, 0); \
        __builtin_amdgcn_s_setprio(0);                                               \
        __builtin_amdgcn_sched_barrier(0);                                           \
        if (DOSTAGE) stageB2(SS);                                                    \
        LGKM(0)                                                                      \
        __builtin_amdgcn_s_setprio(1);                                               \
        _Pragma("unroll")                                                            \
        for (int i = 0; i < 4; ++i)                                                  \
            _Pragma("unroll")                                                        \
            for (int g = 0; g < 4; ++g)                                              \
                acc[4+i][g] = __builtin_amdgcn_mfma_i32_16x16x64_i8(af1[i], bfr[g], acc[4+i][g], 0, 0, 0); \
        __builtin_amdgcn_s_setprio(0);                                               \
        __builtin_amdgcn_sched_barrier(0);                                           \
        if ((CK) == 4) { CKPT4() } else if ((CK) == 1) { CKPT0() }                   \
        BAR()                                                                        \
    }

    // prologue: slices 0,1 -> regions 0,1; drain slice 0 (8 outstanding); sync
    stageA2(0); stageB2(0);
    stageA2(1); stageB2(1);
    CKPT4()
    BAR()

    // 64 slices of 64 K-bytes; stages at SP <= 61 (slice s+2 <= 63)
    for (int s4 = 0; s4 < 15; ++s4) {
        int s = s4 * 4;
        SP(0, s + 2, 1, 4)
        SP(1, s + 3, 1, 4)
        SP(2, s + 4, 1, 4)
        SP(3, s + 5, 1, 4)
    }
    SP(0, 62, 1, 4)   // s=60
    SP(1, 63, 1, 4)   // s=61
    SP(2, 0,  0, 1)   // s=62: CKPT0 drains stage@61 (slice 63) for SP63
    SP(3, 0,  0, 0)   // s=63

    // epilogue: C/D layout col = lane&15, row = (lane>>4)*4 + reg (shape-
    // determined, dtype-independent). out = sx[row]*sw[col]*acc + bias.
    int    colb = bn * 256 + wn * 64;
    size_t rowb = (size_t)bm * 256 + wm * 128 + (lk << 2);
    float sxv[8][4];
    #pragma unroll
    for (int f = 0; f < 8; ++f)
        #pragma unroll
        for (int rg = 0; rg < 4; ++rg)
            sxv[f][rg] = sx[rowb + f * 16 + rg];
    #pragma unroll
    for (int g = 0; g < 4; ++g) {
        int col = colb + g * 16 + l16;
        float scw = sw[col];
        float bv  = bias[col];
        #pragma unroll
        for (int f = 0; f < 8; ++f) {
            size_t r0 = rowb + f * 16;
            #pragma unroll
            for (int rg = 0; rg < 4; ++rg)
                C[(r0 + rg) * N_DIM + col] = (float)acc[f][g][rg] * (sxv[f][rg] * scw) + bv;
        }
    }
}

extern "C" void kernel_launch(void* const* d_in, const int* in_sizes, int n_in,
                              void* d_out, int out_size, void* d_ws, size_t ws_size,
                              hipStream_t stream) {
    const float* x    = (const float*)d_in[0];
    const float* W    = (const float*)d_in[1];
    const float* bias = (const float*)d_in[2];
    float* out = (float*)d_out;

    char* ws = (char*)d_ws;
    int8_t*   xq  = (int8_t*)ws;                                             // 32 MB
    int8_t*   wq  = (int8_t*)(ws + (size_t)M_DIM * K_DIM);                   // 16 MB
    uint16_t* sel = (uint16_t*)(ws + (size_t)M_DIM * K_DIM
                                   + (size_t)N_DIM * K_DIM);                 // 64 KB
    float*    sx  = (float*)((char*)sel + (size_t)(M_DIM / 64) * CBN * 2);   // 32 KB
    float*    sw  = (float*)((char*)sx + (size_t)M_DIM * 4);                 // 16 KB

    venom_sel  <<<dim3(64, 16), 256, 0, stream>>>(W, sel);
    venom_packq<<<dim3(N_DIM), 256, 0, stream>>>(W, sel, wq, sw);
    xq_kernel  <<<dim3(M_DIM), 256, 0, stream>>>(x, xq, sx);
    gemm256_i8 <<<dim3((M_DIM / 256) * (N_DIM / 256)), 512, 0, stream>>>(xq, wq, sx, sw, bias, out);
}